// Round 2
// baseline (4023.608 us; speedup 1.0000x reference)
//
#include <hip/hip_runtime.h>
#include <hip/hip_bf16.h>

typedef __hip_bfloat16 bf16;

#define NN 512      // image N
#define NA 30       // angles
#define ND 729      // detectors
#define NB 2        // batch
#define NL 3        // iterations
#define BNN (NB*NN*NN)     // 524288
#define BAD (NB*NA*ND)     // 43740

// ---- workspace float offsets ----
#define O_CS 0
#define O_SN 32
#define O_X  64
#define O_Z  (O_X + BNN)
#define O_NO (O_Z + BNN)
#define O_SP (O_NO + BNN)
#define O_Q  (O_SP + BAD)
#define O_H  ((O_Q + BAD + 15) & ~15)
// h1/h2: each 32*NN*NN bf16 (one batch image of activations)

__device__ __forceinline__ float ldf(const float* p, int i){ return p[i]; }
__device__ __forceinline__ float ldf(const bf16* p, int i){ return __bfloat162float(p[i]); }
__device__ __forceinline__ void stf(float* p, int i, float v){ p[i] = v; }
__device__ __forceinline__ void stf(bf16* p, int i, float v){ p[i] = __float2bfloat16(v); }

// ---- cos/sin of theta ----
__global__ void k_params(const float* __restrict__ theta, float* __restrict__ ws)
{
    int i = threadIdx.x;
    if (i < NA) {
        float t = theta[i];
        ws[O_CS + i] = cosf(t);
        ws[O_SN + i] = sinf(t);
    }
}

// ---- radon forward: out[b,a,s] = sum_t bilinear(img_b, r(s,t), c(s,t)) ----
// block 256 = 4 waves; wave handles 8 consecutive s; lanes = 8s x 8t patch.
__global__ void k_radon(const float* __restrict__ img, const float* __restrict__ ws,
                        float* __restrict__ out)
{
    int b = blockIdx.z, a = blockIdx.y;
    int wave = threadIdx.x >> 6;
    int lane = threadIdx.x & 63;
    int s_off = lane & 7, t_sub = lane >> 3;
    int s = blockIdx.x * 32 + wave * 8 + s_off;
    float cs = ws[O_CS + a], sn = ws[O_SN + a];
    const float ctr = (NN - 1) * 0.5f;     // 255.5
    const float dctr = (ND - 1) * 0.5f;    // 364
    float s_c = (float)s - dctr;
    const float* im = img + b * NN * NN;
    float acc = 0.f;
    for (int t0 = 0; t0 < ND; t0 += 8) {
        int t = t0 + t_sub;
        if (t < ND && s < ND) {
            float t_c = (float)t - dctr;
            float r = s_c * sn + t_c * cs + ctr;
            float c = s_c * cs - t_c * sn + ctr;
            float rf = floorf(r), cf = floorf(c);
            int ir = (int)rf, ic = (int)cf;
            float dr = r - rf, dc = c - cf;
            float v00 = 0.f, v01 = 0.f, v10 = 0.f, v11 = 0.f;
            bool c0ok = (ic >= 0) && (ic < NN);
            bool c1ok = (ic + 1 >= 0) && (ic + 1 < NN);
            if (ir >= 0 && ir < NN) {
                const float* row = im + ir * NN;
                if (c0ok) v00 = row[ic];
                if (c1ok) v01 = row[ic + 1];
            }
            if (ir + 1 >= 0 && ir + 1 < NN) {
                const float* row = im + (ir + 1) * NN;
                if (c0ok) v10 = row[ic];
                if (c1ok) v11 = row[ic + 1];
            }
            acc += (1.f - dr) * ((1.f - dc) * v00 + dc * v01)
                 +        dr  * ((1.f - dc) * v10 + dc * v11);
        }
    }
    acc += __shfl_down(acc, 32, 64);
    acc += __shfl_down(acc, 16, 64);
    acc += __shfl_down(acc, 8, 64);
    if (t_sub == 0 && s < ND) out[(b * NA + a) * ND + s] = acc;
}

// ---- ramp filter as direct odd-tap convolution ----
// h[0]=0.5, h[m]=-2/(pi m)^2 for odd m, 0 even; no circular wrap since D<P-D.
// mode=1: q = sino - scale*g;  mode=0: q = scale*g
__global__ void k_filter(const float* __restrict__ sp, const float* __restrict__ sino,
                         float* __restrict__ q, int mode)
{
    __shared__ float row[ND];
    __shared__ float taps[364];
    int ba = blockIdx.y;               // 0..59  (= b*NA + a)
    const float* src = sp + ba * ND;
    for (int i = threadIdx.x; i < ND; i += 256) row[i] = src[i];
    const float PI2 = 9.86960440108936f;
    for (int i = threadIdx.x; i < 364; i += 256) {
        float m = (float)(2 * i + 1);
        taps[i] = -2.0f / (PI2 * m * m);
    }
    __syncthreads();
    const float scale = 0.0523598775598299f;  // pi/(2A)
    int d = blockIdx.x * 256 + threadIdx.x;
    if (d < ND) {
        float g = 0.5f * row[d];
        for (int j = 0; j < 364; j++) {
            int m = 2 * j + 1;
            float l = (d - m >= 0) ? row[d - m] : 0.f;
            float r = (d + m < ND) ? row[d + m] : 0.f;
            g = fmaf(taps[j], l + r, g);
        }
        float v = scale * g;
        q[ba * ND + d] = mode ? (sino[ba * ND + d] - v) : v;
    }
}

// ---- backprojection + update:  out = src1 + (src2?src2:0) + sign*steps[n]*backproj(q) ----
__global__ void k_backproj_update(const float* __restrict__ q, const float* __restrict__ src1,
                                  const float* __restrict__ src2, const float* __restrict__ ws,
                                  const float* __restrict__ steps, int n, float sign,
                                  float* __restrict__ out)
{
    int idx = blockIdx.x * 256 + threadIdx.x;     // 0..BNN-1
    int b = idx >> 18;
    int p = idx & (NN * NN - 1);
    int y = p >> 9, x = p & (NN - 1);
    float xc = (float)x - 255.5f, yc = (float)y - 255.5f;
    float acc = 0.f;
    const float* qb = q + b * NA * ND;
    for (int a = 0; a < NA; a++) {
        float cs = ws[O_CS + a], sn = ws[O_SN + a];
        float f = cs * xc + sn * yc + 364.0f;
        float lf = floorf(f);
        int lo = (int)lf;
        float w = f - lf;
        const float* qa = qb + a * ND;
        if (lo >= 0 && lo < ND)         acc += qa[lo] * (1.0f - w);
        if (lo + 1 >= 0 && lo + 1 < ND) acc += qa[lo + 1] * w;
    }
    float step = steps[n] * sign;
    float v = src1[idx] + step * acc;
    if (src2) v += src2[idx];
    out[idx] = v;
}

// ---- direct 3x3 conv, SAME pad, ONE batch image; thread = pixel, all CO accs ----
template<int CI, int CO, bool RELU, bool HASB, typename TIN, typename TOUT>
__global__ __launch_bounds__(256) void k_conv(const TIN* __restrict__ in,
                                              const float* __restrict__ Wt,
                                              const float* __restrict__ Bs,
                                              TOUT* __restrict__ out)
{
    __shared__ float tile[CI][18][20];
    int bx = blockIdx.x, by = blockIdx.y;
    int tid = threadIdx.x;
    for (int idx = tid; idx < CI * 18 * 18; idx += 256) {
        int ci = idx / 324; int r = idx % 324;
        int yy = r / 18, xx = r % 18;
        int gy = by * 16 + yy - 1, gx = bx * 16 + xx - 1;
        float v = 0.f;
        if (gy >= 0 && gy < NN && gx >= 0 && gx < NN)
            v = ldf(in, ci * NN * NN + gy * NN + gx);
        tile[ci][yy][xx] = v;
    }
    __syncthreads();
    int x = tid & 15, y = tid >> 4;
    float acc[CO];
#pragma unroll
    for (int co = 0; co < CO; co++) acc[co] = HASB ? Bs[co] : 0.f;
    for (int ci = 0; ci < CI; ci++) {
        float v[9];
#pragma unroll
        for (int dy = 0; dy < 3; dy++)
#pragma unroll
            for (int dx = 0; dx < 3; dx++)
                v[dy * 3 + dx] = tile[ci][y + dy][x + dx];
        const float* wci = Wt + ci * 9;
#pragma unroll
        for (int co = 0; co < CO; co++) {
            const float* w = wci + co * CI * 9;   // block-uniform -> s_load
#pragma unroll
            for (int k = 0; k < 9; k++) acc[co] = fmaf(v[k], w[k], acc[co]);
        }
    }
    int gy = by * 16 + y, gx = bx * 16 + x;
#pragma unroll
    for (int co = 0; co < CO; co++) {
        float r = acc[co];
        if (RELU) r = fmaxf(r, 0.f);
        stf(out, co * NN * NN + gy * NN + gx, r);
    }
}

// ---- final output: 3 f32 copies of X ----
__global__ void k_output(const float* __restrict__ X, float* __restrict__ out)
{
    int idx = blockIdx.x * 256 + threadIdx.x;
    if (idx < BNN) {
        float v = X[idx];
        out[idx] = v;
        out[idx + BNN] = v;
        out[idx + 2 * BNN] = v;
    }
}

extern "C" void kernel_launch(void* const* d_in, const int* in_sizes, int n_in,
                              void* d_out, int out_size, void* d_ws, size_t ws_size,
                              hipStream_t stream)
{
    const float* x0    = (const float*)d_in[1];
    const float* sg    = (const float*)d_in[2];
    const float* theta = (const float*)d_in[3];
    const float* w1    = (const float*)d_in[5];
    const float* b1    = (const float*)d_in[6];
    const float* w2    = (const float*)d_in[7];
    const float* b2    = (const float*)d_in[8];
    const float* w3    = (const float*)d_in[9];
    const float* b3    = (const float*)d_in[10];
    const float* w4    = (const float*)d_in[11];
    const float* steps = (const float*)d_in[12];

    float* ws = (float*)d_ws;
    float* X  = ws + O_X;
    float* Z  = ws + O_Z;
    float* NO = ws + O_NO;
    float* SP = ws + O_SP;
    float* Q  = ws + O_Q;
    bf16* h1 = (bf16*)(ws + O_H);
    bf16* h2 = h1 + 32 * NN * NN;

    k_params<<<1, 32, 0, stream>>>(theta, ws);

    const float* Xcur = x0;   // iteration 0 reads x0 directly (read-only)
    for (int n = 0; n < NL; n++) {
        // path 1: Xcur -> radon -> filter(sino - .) -> backproj -> Z = Xcur + step*bp
        k_radon<<<dim3(23, NA, NB), 256, 0, stream>>>(Xcur, ws, SP);
        k_filter<<<dim3(3, NB * NA), 256, 0, stream>>>(SP, sg, Q, 1);
        k_backproj_update<<<BNN / 256, 256, 0, stream>>>(Q, Xcur, nullptr, ws, steps, n, 1.0f, Z);

        // denoiser per batch: Xcur -> h1 -> h2 -> h1 -> NO
        for (int b = 0; b < NB; b++) {
            const float* xb = Xcur + b * NN * NN;
            float* nob = NO + b * NN * NN;
            k_conv<1, 32, true, true, float, bf16>
                <<<dim3(32, 32), 256, 0, stream>>>(xb, w1 + n * 288, b1 + n * 32, h1);
            k_conv<32, 32, true, true, bf16, bf16>
                <<<dim3(32, 32), 256, 0, stream>>>(h1, w2 + n * 9216, b2 + n * 32, h2);
            k_conv<32, 32, true, true, bf16, bf16>
                <<<dim3(32, 32), 256, 0, stream>>>(h2, w3 + n * 9216, b3 + n * 32, h1);
            k_conv<32, 1, false, false, bf16, float>
                <<<dim3(32, 32), 256, 0, stream>>>(h1, w4 + n * 288, nullptr, nob);
        }

        // path 2: NO -> radon -> filter -> backproj -> X = Z + NO - step*bp
        k_radon<<<dim3(23, NA, NB), 256, 0, stream>>>(NO, ws, SP);
        k_filter<<<dim3(3, NB * NA), 256, 0, stream>>>(SP, nullptr, Q, 0);
        k_backproj_update<<<BNN / 256, 256, 0, stream>>>(Q, Z, NO, ws, steps, n, -1.0f, X);
        Xcur = X;
    }

    k_output<<<BNN / 256, 256, 0, stream>>>(Xcur, (float*)d_out);
}

// Round 3
// 1327.512 us; speedup vs baseline: 3.0309x; 3.0309x over previous
//
#include <hip/hip_runtime.h>
#include <hip/hip_bf16.h>

typedef __hip_bfloat16 bf16;
typedef __attribute__((ext_vector_type(8))) short short8;
typedef __attribute__((ext_vector_type(4))) float float4v;

#define NN 512      // image N
#define NA 30       // angles
#define ND 729      // detectors
#define NB 2        // batch
#define NL 3        // iterations
#define BNN (NB*NN*NN)     // 524288
#define BAD (NB*NA*ND)     // 43740

// ---- workspace float offsets ----
#define O_CS 0
#define O_SN 32
#define O_X  64
#define O_Z  (O_X + BNN)
#define O_NO (O_Z + BNN)
#define O_SP (O_NO + BNN)
#define O_Q  (O_SP + BAD)
#define O_WR (O_Q + BAD)            // bf16 region: 69120 bf16 (34560 floats)
#define O_H  (((O_WR + 34560) + 15) & ~15)
// h1/h2: each 32*NN*NN bf16 (one batch image of HWC activations)

// repacked weight bf16 offsets within WR region
#define WR2_OFF 0                   // [n][tap][co32][ci32] : 3*9216
#define WR3_OFF 27648               // 3*9216
#define WR4_OFF 55296               // [n][tap][co16][ci32] : 3*4608 (co>0 zero)

// ---- cos/sin of theta ----
__global__ void k_params(const float* __restrict__ theta, float* __restrict__ ws)
{
    int i = threadIdx.x;
    if (i < NA) {
        float t = theta[i];
        ws[O_CS + i] = cosf(t);
        ws[O_SN + i] = sinf(t);
    }
}

// ---- repack conv weights to MFMA B layout: [tap][co][ci] bf16 ----
__global__ void k_prep_w(const float* __restrict__ w2, const float* __restrict__ w3,
                         const float* __restrict__ w4, bf16* __restrict__ wr)
{
    int idx = blockIdx.x * 256 + threadIdx.x;
    if (idx < 2 * 27648) {
        const float* w = (idx < 27648) ? w2 : w3;
        int base = (idx < 27648) ? WR2_OFF : WR3_OFF;
        int r = idx % 27648;
        int n = r / 9216; int r2 = r % 9216;
        int tap = r2 / 1024; int r3 = r2 % 1024;
        int co = r3 / 32, ci = r3 % 32;
        wr[base + r] = __float2bfloat16(w[n * 9216 + (co * 32 + ci) * 9 + tap]);
    } else if (idx < 2 * 27648 + 3 * 4608) {
        int r = idx - 2 * 27648;
        int n = r / 4608; int r2 = r % 4608;
        int tap = r2 / 512; int r3 = r2 % 512;
        int co = r3 / 32, ci = r3 % 32;
        float v = (co == 0) ? w4[n * 288 + ci * 9 + tap] : 0.f;
        wr[WR4_OFF + r] = __float2bfloat16(v);
    }
}

// ---- radon forward: out[b,a,s] = sum_t bilinear(img_b, r(s,t), c(s,t)) ----
__global__ void k_radon(const float* __restrict__ img, const float* __restrict__ ws,
                        float* __restrict__ out)
{
    int b = blockIdx.z, a = blockIdx.y;
    int wave = threadIdx.x >> 6;
    int lane = threadIdx.x & 63;
    int s_off = lane & 7, t_sub = lane >> 3;
    int s = blockIdx.x * 32 + wave * 8 + s_off;
    float cs = ws[O_CS + a], sn = ws[O_SN + a];
    const float ctr = (NN - 1) * 0.5f;
    const float dctr = (ND - 1) * 0.5f;
    float s_c = (float)s - dctr;
    const float* im = img + b * NN * NN;
    float acc = 0.f;
    for (int t0 = 0; t0 < ND; t0 += 8) {
        int t = t0 + t_sub;
        if (t < ND && s < ND) {
            float t_c = (float)t - dctr;
            float r = s_c * sn + t_c * cs + ctr;
            float c = s_c * cs - t_c * sn + ctr;
            float rf = floorf(r), cf = floorf(c);
            int ir = (int)rf, ic = (int)cf;
            float dr = r - rf, dc = c - cf;
            float v00 = 0.f, v01 = 0.f, v10 = 0.f, v11 = 0.f;
            bool c0ok = (ic >= 0) && (ic < NN);
            bool c1ok = (ic + 1 >= 0) && (ic + 1 < NN);
            if (ir >= 0 && ir < NN) {
                const float* row = im + ir * NN;
                if (c0ok) v00 = row[ic];
                if (c1ok) v01 = row[ic + 1];
            }
            if (ir + 1 >= 0 && ir + 1 < NN) {
                const float* row = im + (ir + 1) * NN;
                if (c0ok) v10 = row[ic];
                if (c1ok) v11 = row[ic + 1];
            }
            acc += (1.f - dr) * ((1.f - dc) * v00 + dc * v01)
                 +        dr  * ((1.f - dc) * v10 + dc * v11);
        }
    }
    acc += __shfl_down(acc, 32, 64);
    acc += __shfl_down(acc, 16, 64);
    acc += __shfl_down(acc, 8, 64);
    if (t_sub == 0 && s < ND) out[(b * NA + a) * ND + s] = acc;
}

// ---- ramp filter as direct odd-tap convolution ----
__global__ void k_filter(const float* __restrict__ sp, const float* __restrict__ sino,
                         float* __restrict__ q, int mode)
{
    __shared__ float row[ND];
    __shared__ float taps[364];
    int ba = blockIdx.y;
    const float* src = sp + ba * ND;
    for (int i = threadIdx.x; i < ND; i += 256) row[i] = src[i];
    const float PI2 = 9.86960440108936f;
    for (int i = threadIdx.x; i < 364; i += 256) {
        float m = (float)(2 * i + 1);
        taps[i] = -2.0f / (PI2 * m * m);
    }
    __syncthreads();
    const float scale = 0.0523598775598299f;  // pi/(2A)
    int d = blockIdx.x * 256 + threadIdx.x;
    if (d < ND) {
        float g = 0.5f * row[d];
        for (int j = 0; j < 364; j++) {
            int m = 2 * j + 1;
            float l = (d - m >= 0) ? row[d - m] : 0.f;
            float r = (d + m < ND) ? row[d + m] : 0.f;
            g = fmaf(taps[j], l + r, g);
        }
        float v = scale * g;
        q[ba * ND + d] = mode ? (sino[ba * ND + d] - v) : v;
    }
}

// ---- backprojection + update ----
__global__ void k_backproj_update(const float* __restrict__ q, const float* __restrict__ src1,
                                  const float* __restrict__ src2, const float* __restrict__ ws,
                                  const float* __restrict__ steps, int n, float sign,
                                  float* __restrict__ out)
{
    int idx = blockIdx.x * 256 + threadIdx.x;
    int b = idx >> 18;
    int p = idx & (NN * NN - 1);
    int y = p >> 9, x = p & (NN - 1);
    float xc = (float)x - 255.5f, yc = (float)y - 255.5f;
    float acc = 0.f;
    const float* qb = q + b * NA * ND;
    for (int a = 0; a < NA; a++) {
        float cs = ws[O_CS + a], sn = ws[O_SN + a];
        float f = cs * xc + sn * yc + 364.0f;
        float lf = floorf(f);
        int lo = (int)lf;
        float w = f - lf;
        const float* qa = qb + a * ND;
        if (lo >= 0 && lo < ND)         acc += qa[lo] * (1.0f - w);
        if (lo + 1 >= 0 && lo + 1 < ND) acc += qa[lo + 1] * w;
    }
    float step = steps[n] * sign;
    float v = src1[idx] + step * acc;
    if (src2) v += src2[idx];
    out[idx] = v;
}

// ---- layer 1: direct 1->32 conv, f32 CHW in, bf16 HWC out ----
__global__ __launch_bounds__(256) void k_conv1_hwc(const float* __restrict__ in,
    const float* __restrict__ W, const float* __restrict__ B, bf16* __restrict__ out)
{
    int idx = blockIdx.x * 256 + threadIdx.x;  // pixel in one image
    int y = idx >> 9, x = idx & (NN - 1);
    float v[9];
#pragma unroll
    for (int dy = 0; dy < 3; dy++)
#pragma unroll
        for (int dx = 0; dx < 3; dx++) {
            int yy = y + dy - 1, xx = x + dx - 1;
            v[dy * 3 + dx] = (yy >= 0 && yy < NN && xx >= 0 && xx < NN)
                             ? in[yy * NN + xx] : 0.f;
        }
#pragma unroll
    for (int g = 0; g < 4; g++) {
        short8 pk;
#pragma unroll
        for (int j = 0; j < 8; j++) {
            int co = g * 8 + j;
            float a = B[co];
            const float* w = W + co * 9;   // block-uniform -> s_load
#pragma unroll
            for (int k = 0; k < 9; k++) a = fmaf(v[k], w[k], a);
            a = fmaxf(a, 0.f);
            bf16 h = __float2bfloat16(a);
            pk[j] = *reinterpret_cast<short*>(&h);
        }
        *(short8*)(out + idx * 32 + g * 8) = pk;
    }
}

// ---- MFMA implicit-GEMM 3x3 conv, HWC bf16 in (32 ci) ----
// NCO: # of 16-co tiles (2 => 32 co HWC bf16 out; 1 + OUTF32 => co0 only, f32 CHW out)
// Wave: 16 consecutive pixels in a row x 16/32 co; A-frag = 16B/lane global load.
template<int NCO, bool RELU, bool HASB, bool OUTF32>
__global__ __launch_bounds__(256) void k_conv_mfma(const bf16* __restrict__ in,
    const bf16* __restrict__ Wr, const float* __restrict__ Bs, void* __restrict__ outv)
{
    int lane = threadIdx.x & 63;
    int wave = threadIdx.x >> 6;
    int y = blockIdx.y;
    int x0 = blockIdx.x * 64 + wave * 16;
    int n16 = lane & 15, quad = lane >> 4;

    float4v acc[NCO];
#pragma unroll
    for (int t = 0; t < NCO; t++) {
        float bv = HASB ? Bs[t * 16 + n16] : 0.f;
        acc[t] = (float4v){bv, bv, bv, bv};
    }

#pragma unroll
    for (int dy = 0; dy < 3; dy++) {
        int yy = y + dy - 1;
        if (yy < 0 || yy >= NN) continue;
        const bf16* rowp = in + (size_t)yy * NN * 32;
#pragma unroll
        for (int dx = 0; dx < 3; dx++) {
            int xx = x0 + n16 + dx - 1;
            short8 a = {};
            if (xx >= 0 && xx < NN)
                a = *(const short8*)(rowp + xx * 32 + quad * 8);
            int tap = dy * 3 + dx;
#pragma unroll
            for (int t = 0; t < NCO; t++) {
                short8 b = *(const short8*)(Wr + ((tap * NCO + t) * 16 + n16) * 32 + quad * 8);
                acc[t] = __builtin_amdgcn_mfma_f32_16x16x32_bf16(a, b, acc[t], 0, 0, 0);
            }
        }
    }

    // C layout: col(co)=lane&15, row(pixel)=quad*4+reg
    if (OUTF32) {
        float* out = (float*)outv;
        if (n16 == 0) {
#pragma unroll
            for (int r = 0; r < 4; r++) {
                int px = x0 + quad * 4 + r;
                out[y * NN + px] = acc[0][r];
            }
        }
    } else {
        bf16* out = (bf16*)outv;
#pragma unroll
        for (int r = 0; r < 4; r++) {
            int px = x0 + quad * 4 + r;
            bf16* pp = out + ((size_t)y * NN + px) * 32 + n16;
#pragma unroll
            for (int t = 0; t < NCO; t++) {
                float v = acc[t][r];
                if (RELU) v = fmaxf(v, 0.f);
                pp[t * 16] = __float2bfloat16(v);
            }
        }
    }
}

// ---- final output: 3 f32 copies of X ----
__global__ void k_output(const float* __restrict__ X, float* __restrict__ out)
{
    int idx = blockIdx.x * 256 + threadIdx.x;
    if (idx < BNN) {
        float v = X[idx];
        out[idx] = v;
        out[idx + BNN] = v;
        out[idx + 2 * BNN] = v;
    }
}

extern "C" void kernel_launch(void* const* d_in, const int* in_sizes, int n_in,
                              void* d_out, int out_size, void* d_ws, size_t ws_size,
                              hipStream_t stream)
{
    const float* x0    = (const float*)d_in[1];
    const float* sg    = (const float*)d_in[2];
    const float* theta = (const float*)d_in[3];
    const float* w1    = (const float*)d_in[5];
    const float* b1    = (const float*)d_in[6];
    const float* w2    = (const float*)d_in[7];
    const float* b2    = (const float*)d_in[8];
    const float* w3    = (const float*)d_in[9];
    const float* b3    = (const float*)d_in[10];
    const float* w4    = (const float*)d_in[11];
    const float* steps = (const float*)d_in[12];

    float* ws = (float*)d_ws;
    float* X  = ws + O_X;
    float* Z  = ws + O_Z;
    float* NO = ws + O_NO;
    float* SP = ws + O_SP;
    float* Q  = ws + O_Q;
    bf16* wr  = (bf16*)(ws + O_WR);
    bf16* h1  = (bf16*)(ws + O_H);
    bf16* h2  = h1 + 32 * NN * NN;

    k_params<<<1, 32, 0, stream>>>(theta, ws);
    k_prep_w<<<(2 * 27648 + 3 * 4608 + 255) / 256, 256, 0, stream>>>(w2, w3, w4, wr);

    const float* Xcur = x0;
    for (int n = 0; n < NL; n++) {
        // path 1: Xcur -> radon -> filter(sino - .) -> backproj -> Z
        k_radon<<<dim3(23, NA, NB), 256, 0, stream>>>(Xcur, ws, SP);
        k_filter<<<dim3(3, NB * NA), 256, 0, stream>>>(SP, sg, Q, 1);
        k_backproj_update<<<BNN / 256, 256, 0, stream>>>(Q, Xcur, nullptr, ws, steps, n, 1.0f, Z);

        // denoiser per batch: Xcur -> h1 -> h2 -> h1 -> NO
        for (int b = 0; b < NB; b++) {
            const float* xb = Xcur + b * NN * NN;
            float* nob = NO + b * NN * NN;
            k_conv1_hwc<<<NN * NN / 256, 256, 0, stream>>>(xb, w1 + n * 288, b1 + n * 32, h1);
            k_conv_mfma<2, true, true, false><<<dim3(8, NN), 256, 0, stream>>>(
                h1, wr + WR2_OFF + n * 9216, b2 + n * 32, h2);
            k_conv_mfma<2, true, true, false><<<dim3(8, NN), 256, 0, stream>>>(
                h2, wr + WR3_OFF + n * 9216, b3 + n * 32, h1);
            k_conv_mfma<1, false, false, true><<<dim3(8, NN), 256, 0, stream>>>(
                h1, wr + WR4_OFF + n * 4608, nullptr, nob);
        }

        // path 2: NO -> radon -> filter -> backproj -> X
        k_radon<<<dim3(23, NA, NB), 256, 0, stream>>>(NO, ws, SP);
        k_filter<<<dim3(3, NB * NA), 256, 0, stream>>>(SP, nullptr, Q, 0);
        k_backproj_update<<<BNN / 256, 256, 0, stream>>>(Q, Z, NO, ws, steps, n, -1.0f, X);
        Xcur = X;
    }

    k_output<<<BNN / 256, 256, 0, stream>>>(Xcur, (float*)d_out);
}

// Round 4
// 1014.030 us; speedup vs baseline: 3.9679x; 1.3091x over previous
//
#include <hip/hip_runtime.h>
#include <hip/hip_bf16.h>

typedef __hip_bfloat16 bf16;
typedef __attribute__((ext_vector_type(8))) short short8;
typedef __attribute__((ext_vector_type(4))) float float4v;

#define NN 512      // image N
#define NA 30       // angles
#define ND 729      // detectors
#define NB 2        // batch
#define NL 3        // iterations
#define BNN (NB*NN*NN)     // 524288
#define BAD (NB*NA*ND)     // 43740

// padded image layout: PH x PW, logical (0,0) at physical (2,2)
#define PW 520
#define PH 516
#define PIMG (PH*PW)       // 268320
#define POFF (2*PW + 2)    // 1042

// ---- workspace float offsets ----
#define O_CS 0
#define O_SN 32
#define O_XP 64                       // 2*PIMG (X, also holds padded x0 initially)
#define O_ZP (O_XP + 2*PIMG)          // 2*PIMG
#define O_NOP (O_ZP + 2*PIMG)         // 2*PIMG
#define O_SP (O_NOP + 2*PIMG)         // BAD
#define O_Q  (O_SP + BAD)             // BAD
#define O_WR (O_Q + BAD)              // bf16 region: 69120 bf16 = 34560 floats
#define O_H  (((O_WR + 34560) + 15) & ~15)
// h1/h2: each 32*NN*NN bf16

// repacked weight bf16 offsets within WR region
#define WR2_OFF 0                   // [n][tap][co32][ci32] : 3*9216
#define WR3_OFF 27648               // 3*9216
#define WR4_OFF 55296               // [n][tap][co16][ci32] : 3*4608 (co>0 zero)

// ---- cos/sin of theta ----
__global__ void k_params(const float* __restrict__ theta, float* __restrict__ ws)
{
    int i = threadIdx.x;
    if (i < NA) {
        float t = theta[i];
        ws[O_CS + i] = cosf(t);
        ws[O_SN + i] = sinf(t);
    }
}

// ---- init: XP = padded(x0) (border zero), NOP border zero ----
__global__ void k_init_pad(const float* __restrict__ x0, float* __restrict__ XP,
                           float* __restrict__ NOP)
{
    int idx = blockIdx.x * 256 + threadIdx.x;
    if (idx >= 2 * PIMG) return;
    int b = idx / PIMG, p = idx % PIMG;
    int y = p / PW, x = p % PW;
    bool interior = (y >= 2 && y < 2 + NN && x >= 2 && x < 2 + NN);
    float v = interior ? x0[b * NN * NN + (y - 2) * NN + (x - 2)] : 0.f;
    XP[idx] = v;
    if (!interior) NOP[idx] = 0.f;
}

// ---- repack conv weights to MFMA B layout: [tap][co][ci] bf16 ----
__global__ void k_prep_w(const float* __restrict__ w2, const float* __restrict__ w3,
                         const float* __restrict__ w4, bf16* __restrict__ wr)
{
    int idx = blockIdx.x * 256 + threadIdx.x;
    if (idx < 2 * 27648) {
        const float* w = (idx < 27648) ? w2 : w3;
        int base = (idx < 27648) ? WR2_OFF : WR3_OFF;
        int r = idx % 27648;
        int n = r / 9216; int r2 = r % 9216;
        int tap = r2 / 1024; int r3 = r2 % 1024;
        int co = r3 / 32, ci = r3 % 32;
        wr[base + r] = __float2bfloat16(w[n * 9216 + (co * 32 + ci) * 9 + tap]);
    } else if (idx < 2 * 27648 + 3 * 4608) {
        int r = idx - 2 * 27648;
        int n = r / 4608; int r2 = r % 4608;
        int tap = r2 / 512; int r3 = r2 % 512;
        int co = r3 / 32, ci = r3 % 32;
        float v = (co == 0) ? w4[n * 288 + ci * 9 + tap] : 0.f;
        wr[WR4_OFF + r] = __float2bfloat16(v);
    }
}

// intersect t-interval with constraint: lo < A + tc*coef < hi
__device__ __forceinline__ void isect(float A, float coef, float lo, float hi,
                                      float& tlo, float& thi)
{
    float a = (lo - A) / coef, b = (hi - A) / coef;
    float l = fminf(a, b), h = fmaxf(a, b);
    tlo = fmaxf(tlo, l);   // NaN (0/0) is ignored by fmaxf/fminf -> safe (see notes)
    thi = fminf(thi, h);
}

// ---- radon forward over padded image; chord-clipped t loop ----
// wave = 8s x 8t patch; wave-uniform [wb,we] = union of per-lane chords.
__global__ __launch_bounds__(256) void k_radon(const float* __restrict__ img,
    const float* __restrict__ ws, float* __restrict__ out)
{
    int b = blockIdx.z, a = blockIdx.y;
    int wave = threadIdx.x >> 6;
    int lane = threadIdx.x & 63;
    int s_off = lane & 7, t_sub = lane >> 3;
    int s = blockIdx.x * 32 + wave * 8 + s_off;
    float cs = ws[O_CS + a], sn = ws[O_SN + a];
    float s_c = (float)s - 364.0f;
    float A_r = 255.5f + s_c * sn;    // r(t) = A_r + tc*cs
    float A_c = 255.5f + s_c * cs;    // c(t) = A_c - tc*sn

    float tlo = -1e9f, thi = 1e9f;
    isect(A_r, cs, -1.0f, 512.0f, tlo, thi);
    isect(A_c, -sn, -1.0f, 512.0f, tlo, thi);
    float t0f = fmaxf(tlo + 364.0f, 0.0f);
    float t1f = fminf(thi + 364.0f, 728.0f);
    int tb, te;
    if (s >= ND || t0f > t1f) { tb = 729; te = -1; }
    else { tb = (int)ceilf(t0f); te = (int)floorf(t1f); }

    int wb = tb, we = te;
    wb = min(wb, __shfl_xor(wb, 1, 64)); we = max(we, __shfl_xor(we, 1, 64));
    wb = min(wb, __shfl_xor(wb, 2, 64)); we = max(we, __shfl_xor(we, 2, 64));
    wb = min(wb, __shfl_xor(wb, 4, 64)); we = max(we, __shfl_xor(we, 4, 64));

    const float* im = img + b * PIMG;
    float acc = 0.f;
#pragma unroll 2
    for (int t = wb + t_sub; t <= we; t += 8) {
        if (t >= tb && t <= te) {
            float tc = (float)t - 364.0f;
            float r = fmaf(tc, cs, A_r);
            float c = fmaf(-tc, sn, A_c);
            float rf = floorf(r), cf = floorf(c);
            float dr = r - rf, dc = c - cf;
            int idx = (int)rf * PW + (int)cf;
            float v00 = im[idx], v01 = im[idx + 1];
            float v10 = im[idx + PW], v11 = im[idx + PW + 1];
            float top = fmaf(dc, v01 - v00, v00);
            float bot = fmaf(dc, v11 - v10, v10);
            acc = fmaf(dr, bot - top, acc + top);
        }
    }
    acc += __shfl_down(acc, 32, 64);
    acc += __shfl_down(acc, 16, 64);
    acc += __shfl_down(acc, 8, 64);
    if (t_sub == 0 && s < ND) out[(b * NA + a) * ND + s] = acc;
}

// ---- ramp filter as direct odd-tap convolution ----
__global__ void k_filter(const float* __restrict__ sp, const float* __restrict__ sino,
                         float* __restrict__ q, int mode)
{
    __shared__ float row[ND];
    __shared__ float taps[364];
    int ba = blockIdx.y;
    const float* src = sp + ba * ND;
    for (int i = threadIdx.x; i < ND; i += 256) row[i] = src[i];
    const float PI2 = 9.86960440108936f;
    for (int i = threadIdx.x; i < 364; i += 256) {
        float m = (float)(2 * i + 1);
        taps[i] = -2.0f / (PI2 * m * m);
    }
    __syncthreads();
    const float scale = 0.0523598775598299f;  // pi/(2A)
    int d = blockIdx.x * 256 + threadIdx.x;
    if (d < ND) {
        float g0 = 0.5f * row[d], g1 = 0.f;
#pragma unroll 4
        for (int j = 0; j < 364; j += 2) {
            int m0 = 2 * j + 1, m1 = 2 * j + 3;
            float l0 = (d - m0 >= 0) ? row[d - m0] : 0.f;
            float r0 = (d + m0 < ND) ? row[d + m0] : 0.f;
            g0 = fmaf(taps[j], l0 + r0, g0);
            float l1 = (d - m1 >= 0) ? row[d - m1] : 0.f;
            float r1 = (d + m1 < ND) ? row[d + m1] : 0.f;
            g1 = fmaf(taps[j + 1], l1 + r1, g1);
        }
        float v = scale * (g0 + g1);
        q[ba * ND + d] = mode ? (sino[ba * ND + d] - v) : v;
    }
}

// ---- backprojection + update (all image ptrs padded, origin-adjusted) ----
// out = src1 + (src2?src2:0) + sign*steps[n]*backproj(q)
__global__ __launch_bounds__(256) void k_backproj_update(const float* __restrict__ q,
    const float* __restrict__ src1, const float* __restrict__ src2,
    const float* __restrict__ ws, const float* __restrict__ steps, int n, float sign,
    float* __restrict__ out)
{
    int idx = blockIdx.x * 256 + threadIdx.x;
    int b = idx >> 18;
    int p = idx & (NN * NN - 1);
    int y = p >> 9, x = p & (NN - 1);
    int pidx = b * PIMG + y * PW + x;
    float xc = (float)x - 255.5f, yc = (float)y - 255.5f;
    float acc = 0.f;
    const float* qb = q + b * NA * ND;
#pragma unroll
    for (int a = 0; a < NA; a++) {
        float cs = ws[O_CS + a], sn = ws[O_SN + a];
        float f = fmaf(cs, xc, fmaf(sn, yc, 364.0f));
        float lf = floorf(f);
        int lo = (int)lf;              // provably in [2,726]
        float w = f - lf;
        const float* qa = qb + a * ND;
        acc = fmaf(qa[lo], 1.0f - w, acc);
        acc = fmaf(qa[lo + 1], w, acc);
    }
    float step = steps[n] * sign;
    float v = fmaf(step, acc, src1[pidx]);
    if (src2) v += src2[pidx];
    out[pidx] = v;
}

// ---- layer 1: direct 1->32 conv, padded f32 in, bf16 HWC out ----
__global__ __launch_bounds__(256) void k_conv1_hwc(const float* __restrict__ in,
    const float* __restrict__ W, const float* __restrict__ B, bf16* __restrict__ out)
{
    int idx = blockIdx.x * 256 + threadIdx.x;  // pixel in one image
    int y = idx >> 9, x = idx & (NN - 1);
    float v[9];
#pragma unroll
    for (int dy = 0; dy < 3; dy++)
#pragma unroll
        for (int dx = 0; dx < 3; dx++)
            v[dy * 3 + dx] = in[(y + dy - 1) * PW + (x + dx - 1)];
#pragma unroll
    for (int g = 0; g < 4; g++) {
        short8 pk;
#pragma unroll
        for (int j = 0; j < 8; j++) {
            int co = g * 8 + j;
            float a = B[co];
            const float* w = W + co * 9;   // block-uniform -> s_load
#pragma unroll
            for (int k = 0; k < 9; k++) a = fmaf(v[k], w[k], a);
            a = fmaxf(a, 0.f);
            bf16 h = __float2bfloat16(a);
            pk[j] = *reinterpret_cast<short*>(&h);
        }
        *(short8*)(out + idx * 32 + g * 8) = pk;
    }
}

// ---- MFMA implicit-GEMM 3x3 conv, HWC bf16 in (32 ci) ----
// NCO=2: 32-co bf16 HWC out. NCO=1+OUTF32: co0 only, f32 PADDED out.
template<int NCO, bool RELU, bool HASB, bool OUTF32>
__global__ __launch_bounds__(256) void k_conv_mfma(const bf16* __restrict__ in,
    const bf16* __restrict__ Wr, const float* __restrict__ Bs, void* __restrict__ outv)
{
    int lane = threadIdx.x & 63;
    int wave = threadIdx.x >> 6;
    int y = blockIdx.y;
    int x0 = blockIdx.x * 64 + wave * 16;
    int n16 = lane & 15, quad = lane >> 4;

    float4v acc[NCO];
#pragma unroll
    for (int t = 0; t < NCO; t++) {
        float bv = HASB ? Bs[t * 16 + n16] : 0.f;
        acc[t] = (float4v){bv, bv, bv, bv};
    }

#pragma unroll
    for (int dy = 0; dy < 3; dy++) {
        int yy = y + dy - 1;
        if (yy < 0 || yy >= NN) continue;
        const bf16* rowp = in + (size_t)yy * NN * 32;
#pragma unroll
        for (int dx = 0; dx < 3; dx++) {
            int xx = x0 + n16 + dx - 1;
            short8 a = {};
            if (xx >= 0 && xx < NN)
                a = *(const short8*)(rowp + xx * 32 + quad * 8);
            int tap = dy * 3 + dx;
#pragma unroll
            for (int t = 0; t < NCO; t++) {
                short8 b = *(const short8*)(Wr + ((tap * NCO + t) * 16 + n16) * 32 + quad * 8);
                acc[t] = __builtin_amdgcn_mfma_f32_16x16x32_bf16(a, b, acc[t], 0, 0, 0);
            }
        }
    }

    // C layout: col(co)=lane&15, row(pixel)=quad*4+reg
    if (OUTF32) {
        float* out = (float*)outv;
        if (n16 == 0) {
#pragma unroll
            for (int r = 0; r < 4; r++) {
                int px = x0 + quad * 4 + r;
                out[y * PW + px] = acc[0][r];
            }
        }
    } else {
        bf16* out = (bf16*)outv;
#pragma unroll
        for (int r = 0; r < 4; r++) {
            int px = x0 + quad * 4 + r;
            bf16* pp = out + ((size_t)y * NN + px) * 32 + n16;
#pragma unroll
            for (int t = 0; t < NCO; t++) {
                float v = acc[t][r];
                if (RELU) v = fmaxf(v, 0.f);
                pp[t * 16] = __float2bfloat16(v);
            }
        }
    }
}

// ---- final output: 3 f32 copies of padded X ----
__global__ void k_output(const float* __restrict__ X, float* __restrict__ out)
{
    int idx = blockIdx.x * 256 + threadIdx.x;
    if (idx < BNN) {
        int b = idx >> 18;
        int p = idx & (NN * NN - 1);
        int y = p >> 9, x = p & (NN - 1);
        float v = X[b * PIMG + y * PW + x];
        out[idx] = v;
        out[idx + BNN] = v;
        out[idx + 2 * BNN] = v;
    }
}

extern "C" void kernel_launch(void* const* d_in, const int* in_sizes, int n_in,
                              void* d_out, int out_size, void* d_ws, size_t ws_size,
                              hipStream_t stream)
{
    const float* x0    = (const float*)d_in[1];
    const float* sg    = (const float*)d_in[2];
    const float* theta = (const float*)d_in[3];
    const float* w1    = (const float*)d_in[5];
    const float* b1    = (const float*)d_in[6];
    const float* w2    = (const float*)d_in[7];
    const float* b2    = (const float*)d_in[8];
    const float* w3    = (const float*)d_in[9];
    const float* b3    = (const float*)d_in[10];
    const float* w4    = (const float*)d_in[11];
    const float* steps = (const float*)d_in[12];

    float* ws = (float*)d_ws;
    float* XP  = ws + O_XP + POFF;    // origin-adjusted padded pointers
    float* ZP  = ws + O_ZP + POFF;
    float* NOP = ws + O_NOP + POFF;
    float* SP = ws + O_SP;
    float* Q  = ws + O_Q;
    bf16* wr  = (bf16*)(ws + O_WR);
    bf16* h1  = (bf16*)(ws + O_H);
    bf16* h2  = h1 + 32 * NN * NN;

    k_params<<<1, 32, 0, stream>>>(theta, ws);
    k_init_pad<<<(2 * PIMG + 255) / 256, 256, 0, stream>>>(x0, ws + O_XP, ws + O_NOP);
    k_prep_w<<<(2 * 27648 + 3 * 4608 + 255) / 256, 256, 0, stream>>>(w2, w3, w4, wr);

    for (int n = 0; n < NL; n++) {
        // path 1: XP -> radon -> filter(sino - .) -> backproj -> ZP
        k_radon<<<dim3(23, NA, NB), 256, 0, stream>>>(XP, ws, SP);
        k_filter<<<dim3(3, NB * NA), 256, 0, stream>>>(SP, sg, Q, 1);
        k_backproj_update<<<BNN / 256, 256, 0, stream>>>(Q, XP, nullptr, ws, steps, n, 1.0f, ZP);

        // denoiser per batch: XP -> h1 -> h2 -> h1 -> NOP
        for (int b = 0; b < NB; b++) {
            k_conv1_hwc<<<NN * NN / 256, 256, 0, stream>>>(XP + b * PIMG, w1 + n * 288, b1 + n * 32, h1);
            k_conv_mfma<2, true, true, false><<<dim3(8, NN), 256, 0, stream>>>(
                h1, wr + WR2_OFF + n * 9216, b2 + n * 32, h2);
            k_conv_mfma<2, true, true, false><<<dim3(8, NN), 256, 0, stream>>>(
                h2, wr + WR3_OFF + n * 9216, b3 + n * 32, h1);
            k_conv_mfma<1, false, false, true><<<dim3(8, NN), 256, 0, stream>>>(
                h1, wr + WR4_OFF + n * 4608, nullptr, NOP + b * PIMG);
        }

        // path 2: NOP -> radon -> filter -> backproj -> XP = ZP + NOP - step*bp
        k_radon<<<dim3(23, NA, NB), 256, 0, stream>>>(NOP, ws, SP);
        k_filter<<<dim3(3, NB * NA), 256, 0, stream>>>(SP, nullptr, Q, 0);
        k_backproj_update<<<BNN / 256, 256, 0, stream>>>(Q, ZP, NOP, ws, steps, n, -1.0f, XP);
    }

    k_output<<<BNN / 256, 256, 0, stream>>>(XP, (float*)d_out);
}

// Round 6
// 687.934 us; speedup vs baseline: 5.8488x; 1.4740x over previous
//
#include <hip/hip_runtime.h>
#include <hip/hip_bf16.h>

typedef __hip_bfloat16 bf16;
typedef __attribute__((ext_vector_type(8))) short short8;
typedef __attribute__((ext_vector_type(4))) short s4v;
typedef __attribute__((ext_vector_type(4))) float float4v;

#define NN 512      // image N
#define NA 30       // angles
#define ND 729      // detectors
#define NB 2        // batch
#define NL 3        // iterations
#define BNN (NB*NN*NN)     // 524288
#define BAD (NB*NA*ND)     // 43740

// padded image layout: PH x PW, logical (0,0) at physical (2,2)
#define PW 520
#define PH 516
#define PIMG (PH*PW)       // 268320
#define POFF (2*PW + 2)    // 1042

// ---- workspace float offsets ----
#define O_CS 0
#define O_SN 32
#define O_XP 64                       // 2*PIMG
#define O_ZP (O_XP + 2*PIMG)          // 2*PIMG
#define O_NOP (O_ZP + 2*PIMG)         // 2*PIMG
#define O_SP (O_NOP + 2*PIMG)         // BAD
#define O_Q  (O_SP + BAD)             // BAD
#define O_WR (O_Q + BAD)              // bf16 region: 69120 bf16 = 34560 floats
#define O_H  (((O_WR + 34560) + 15) & ~15)
// h1/h2: each NB*32*NN*NN bf16 = 8388608 floats

#define H_FLOATS (NB * 32 * NN * NN / 2)

// repacked weight bf16 offsets within WR region
#define WR2_OFF 0                   // [n][tap][co32][ci32] : 3*9216
#define WR3_OFF 27648               // 3*9216
#define WR4_OFF 55296               // [n][tap][co16][ci32] : 3*4608 (co>0 zero)

// ---- cos/sin of theta ----
__global__ void k_params(const float* __restrict__ theta, float* __restrict__ ws)
{
    int i = threadIdx.x;
    if (i < NA) {
        float t = theta[i];
        ws[O_CS + i] = cosf(t);
        ws[O_SN + i] = sinf(t);
    }
}

// ---- init: XP = padded(x0) (border zero), NOP border zero ----
__global__ void k_init_pad(const float* __restrict__ x0, float* __restrict__ XP,
                           float* __restrict__ NOP)
{
    int idx = blockIdx.x * 256 + threadIdx.x;
    if (idx >= 2 * PIMG) return;
    int b = idx / PIMG, p = idx % PIMG;
    int y = p / PW, x = p % PW;
    bool interior = (y >= 2 && y < 2 + NN && x >= 2 && x < 2 + NN);
    float v = interior ? x0[b * NN * NN + (y - 2) * NN + (x - 2)] : 0.f;
    XP[idx] = v;
    if (!interior) NOP[idx] = 0.f;
}

// ---- repack conv weights to MFMA [tap][co-tile][co16][ci32] bf16 ----
__global__ void k_prep_w(const float* __restrict__ w2, const float* __restrict__ w3,
                         const float* __restrict__ w4, bf16* __restrict__ wr)
{
    int idx = blockIdx.x * 256 + threadIdx.x;
    if (idx < 2 * 27648) {
        const float* w = (idx < 27648) ? w2 : w3;
        int base = (idx < 27648) ? WR2_OFF : WR3_OFF;
        int r = idx % 27648;
        int n = r / 9216; int r2 = r % 9216;
        int tap = r2 / 1024; int r3 = r2 % 1024;
        int co = r3 / 32, ci = r3 % 32;
        wr[base + r] = __float2bfloat16(w[n * 9216 + (co * 32 + ci) * 9 + tap]);
    } else if (idx < 2 * 27648 + 3 * 4608) {
        int r = idx - 2 * 27648;
        int n = r / 4608; int r2 = r % 4608;
        int tap = r2 / 512; int r3 = r2 % 512;
        int co = r3 / 32, ci = r3 % 32;
        float v = (co == 0) ? w4[n * 288 + ci * 9 + tap] : 0.f;
        wr[WR4_OFF + r] = __float2bfloat16(v);
    }
}

// intersect t-interval with constraint: lo < A + tc*coef < hi
__device__ __forceinline__ void isect(float A, float coef, float lo, float hi,
                                      float& tlo, float& thi)
{
    float a = (lo - A) / coef, b = (hi - A) / coef;
    float l = fminf(a, b), h = fmaxf(a, b);
    tlo = fmaxf(tlo, l);
    thi = fminf(thi, h);
}

// ---- radon forward over padded image; chord-clipped t loop ----
__global__ __launch_bounds__(256) void k_radon(const float* __restrict__ img,
    const float* __restrict__ ws, float* __restrict__ out)
{
    int b = blockIdx.z, a = blockIdx.y;
    int wave = threadIdx.x >> 6;
    int lane = threadIdx.x & 63;
    int s_off = lane & 7, t_sub = lane >> 3;
    int s = blockIdx.x * 32 + wave * 8 + s_off;
    float cs = ws[O_CS + a], sn = ws[O_SN + a];
    float s_c = (float)s - 364.0f;
    float A_r = 255.5f + s_c * sn;    // r(t) = A_r + tc*cs
    float A_c = 255.5f + s_c * cs;    // c(t) = A_c - tc*sn

    float tlo = -1e9f, thi = 1e9f;
    isect(A_r, cs, -1.0f, 512.0f, tlo, thi);
    isect(A_c, -sn, -1.0f, 512.0f, tlo, thi);
    float t0f = fmaxf(tlo + 364.0f, 0.0f);
    float t1f = fminf(thi + 364.0f, 728.0f);
    int tb, te;
    if (s >= ND || t0f > t1f) { tb = 729; te = -1; }
    else { tb = (int)ceilf(t0f); te = (int)floorf(t1f); }

    int wb = tb, we = te;
    wb = min(wb, __shfl_xor(wb, 1, 64)); we = max(we, __shfl_xor(we, 1, 64));
    wb = min(wb, __shfl_xor(wb, 2, 64)); we = max(we, __shfl_xor(we, 2, 64));
    wb = min(wb, __shfl_xor(wb, 4, 64)); we = max(we, __shfl_xor(we, 4, 64));

    const float* im = img + b * PIMG;
    float acc = 0.f;
#pragma unroll 2
    for (int t = wb + t_sub; t <= we; t += 8) {
        if (t >= tb && t <= te) {
            float tc = (float)t - 364.0f;
            float r = fmaf(tc, cs, A_r);
            float c = fmaf(-tc, sn, A_c);
            float rf = floorf(r), cf = floorf(c);
            float dr = r - rf, dc = c - cf;
            int idx = (int)rf * PW + (int)cf;
            float v00 = im[idx], v01 = im[idx + 1];
            float v10 = im[idx + PW], v11 = im[idx + PW + 1];
            float top = fmaf(dc, v01 - v00, v00);
            float bot = fmaf(dc, v11 - v10, v10);
            acc = fmaf(dr, bot - top, acc + top);
        }
    }
    acc += __shfl_down(acc, 32, 64);
    acc += __shfl_down(acc, 16, 64);
    acc += __shfl_down(acc, 8, 64);
    if (t_sub == 0 && s < ND) out[(b * NA + a) * ND + s] = acc;
}

// ---- ramp filter as direct odd-tap convolution ----
__global__ void k_filter(const float* __restrict__ sp, const float* __restrict__ sino,
                         float* __restrict__ q, int mode)
{
    __shared__ float row[ND];
    __shared__ float taps[364];
    int ba = blockIdx.y;
    const float* src = sp + ba * ND;
    for (int i = threadIdx.x; i < ND; i += 256) row[i] = src[i];
    const float PI2 = 9.86960440108936f;
    for (int i = threadIdx.x; i < 364; i += 256) {
        float m = (float)(2 * i + 1);
        taps[i] = -2.0f / (PI2 * m * m);
    }
    __syncthreads();
    const float scale = 0.0523598775598299f;  // pi/(2A)
    int d = blockIdx.x * 256 + threadIdx.x;
    if (d < ND) {
        float g0 = 0.5f * row[d], g1 = 0.f;
#pragma unroll 4
        for (int j = 0; j < 364; j += 2) {
            int m0 = 2 * j + 1, m1 = 2 * j + 3;
            float l0 = (d - m0 >= 0) ? row[d - m0] : 0.f;
            float r0 = (d + m0 < ND) ? row[d + m0] : 0.f;
            g0 = fmaf(taps[j], l0 + r0, g0);
            float l1 = (d - m1 >= 0) ? row[d - m1] : 0.f;
            float r1 = (d + m1 < ND) ? row[d + m1] : 0.f;
            g1 = fmaf(taps[j + 1], l1 + r1, g1);
        }
        float v = scale * (g0 + g1);
        q[ba * ND + d] = mode ? (sino[ba * ND + d] - v) : v;
    }
}

// ---- LDS-tiled backprojection + update ----
// 16x16 px tile; per-angle d-window (<=23 wide) staged in LDS.
__global__ __launch_bounds__(256) void k_backproj_update(const float* __restrict__ q,
    const float* __restrict__ src1, const float* __restrict__ src2,
    const float* __restrict__ ws, const float* __restrict__ steps, int n, float sign,
    float* __restrict__ out)
{
    __shared__ float qt[NA][28];
    __shared__ int dmin_s[NA];
    int b = blockIdx.z;
    int x0 = blockIdx.x * 16, y0 = blockIdx.y * 16;
    int tid = threadIdx.x;
    int lx = tid & 15, ly = tid >> 4;
    const float* qb = q + b * NA * ND;

    for (int idx = tid; idx < NA * 26; idx += 256) {
        int a = idx / 26, j = idx % 26;
        float cs = ws[O_CS + a], sn = ws[O_SN + a];
        float f00 = fmaf(cs, (float)x0 - 255.5f, fmaf(sn, (float)y0 - 255.5f, 364.0f));
        float fmn = f00 + fminf(cs * 15.f, 0.f) + fminf(sn * 15.f, 0.f);
        int dm = (int)floorf(fmn);
        if (j == 0) dmin_s[a] = dm;
        int d = dm + j;
        qt[a][j] = (d >= 0 && d < ND) ? qb[a * ND + d] : 0.f;
    }
    __syncthreads();

    float xc = (float)(x0 + lx) - 255.5f, yc = (float)(y0 + ly) - 255.5f;
    float acc = 0.f;
#pragma unroll
    for (int a = 0; a < NA; a++) {
        float cs = ws[O_CS + a], sn = ws[O_SN + a];
        float f = fmaf(cs, xc, fmaf(sn, yc, 364.0f));
        float lf = floorf(f);
        float w = f - lf;
        int j = (int)lf - dmin_s[a];
        float v0 = qt[a][j], v1 = qt[a][j + 1];
        acc = fmaf(v0, 1.0f - w, fmaf(v1, w, acc));
    }
    int pidx = b * PIMG + (y0 + ly) * PW + (x0 + lx);
    float step = steps[n] * sign;
    float v = fmaf(step, acc, src1[pidx]);
    if (src2) v += src2[pidx];
    out[pidx] = v;
}

// ---- layer 1: direct 1->32 conv, padded f32 in, bf16 HWC out; grid.y = batch ----
__global__ __launch_bounds__(256) void k_conv1_hwc(const float* __restrict__ inb,
    const float* __restrict__ W, const float* __restrict__ B, bf16* __restrict__ outb)
{
    int bz = blockIdx.y;
    const float* in = inb + bz * PIMG;
    bf16* out = outb + (size_t)bz * NN * NN * 32;
    int idx = blockIdx.x * 256 + threadIdx.x;
    int y = idx >> 9, x = idx & (NN - 1);
    float v[9];
#pragma unroll
    for (int dy = 0; dy < 3; dy++)
#pragma unroll
        for (int dx = 0; dx < 3; dx++)
            v[dy * 3 + dx] = in[(y + dy - 1) * PW + (x + dx - 1)];
#pragma unroll
    for (int g = 0; g < 4; g++) {
        short8 pk;
#pragma unroll
        for (int j = 0; j < 8; j++) {
            int co = g * 8 + j;
            float a = B[co];
            const float* w = W + co * 9;
#pragma unroll
            for (int k = 0; k < 9; k++) a = fmaf(v[k], w[k], a);
            a = fmaxf(a, 0.f);
            bf16 h = __float2bfloat16(a);
            pk[j] = *reinterpret_cast<short*>(&h);
        }
        *(short8*)(out + (size_t)idx * 32 + g * 8) = pk;
    }
}

// ---- streaming MFMA implicit-GEMM 3x3 conv, HWC bf16 in (32 ci) ----
// Operands swapped vs naive: W = A-operand (m=co), pixels = B-operand (n=px).
// C: col=lane&15=px, row=quad*4+reg=co -> 8B-packed co stores.
// Wave: 16 px (x) strip of SH rows, weights in registers, 3-row rolling window.
#define SH 8
template<int NCO, bool RELU, bool HASB, bool OUTF32>
__global__ __launch_bounds__(256) void k_conv_stream(const bf16* __restrict__ inb,
    const bf16* __restrict__ Wr, const float* __restrict__ Bs, void* __restrict__ outv)
{
    int lane = threadIdx.x & 63;
    int wave = threadIdx.x >> 6;
    int n16 = lane & 15, quad = lane >> 4;
    int b = blockIdx.z;
    int x0 = blockIdx.x * 16;
    int y0 = (blockIdx.y * 4 + wave) * SH;
    const bf16* in = inb + (size_t)b * NN * NN * 32;

    short8 wf[9 * NCO];
#pragma unroll
    for (int tap = 0; tap < 9; tap++)
#pragma unroll
        for (int t = 0; t < NCO; t++)
            wf[tap * NCO + t] = *(const short8*)(Wr + ((tap * NCO + t) * 16 + n16) * 32 + quad * 8);

    bool vx[3];
#pragma unroll
    for (int dx = 0; dx < 3; dx++) {
        int xx = x0 + n16 + dx - 1;
        vx[dx] = (xx >= 0) && (xx < NN);
    }

    short8 win[3][3];
    auto loadrow = [&](int yy, short8* dst) {
        if (yy >= 0 && yy < NN) {
            const bf16* rowp = in + (size_t)yy * NN * 32;
#pragma unroll
            for (int dx = 0; dx < 3; dx++) {
                short8 v = {};
                if (vx[dx]) v = *(const short8*)(rowp + (x0 + n16 + dx - 1) * 32 + quad * 8);
                dst[dx] = v;
            }
        } else {
            dst[0] = short8{}; dst[1] = short8{}; dst[2] = short8{};
        }
    };
    loadrow(y0 - 1, win[0]);
    loadrow(y0,     win[1]);

    float4v bias[NCO];
#pragma unroll
    for (int t = 0; t < NCO; t++)
        bias[t] = HASB ? *(const float4v*)(Bs + t * 16 + quad * 4) : (float4v){0.f, 0.f, 0.f, 0.f};

#pragma unroll
    for (int i = 0; i < SH; i++) {
        int y = y0 + i;
        loadrow(y + 1, win[(i + 2) % 3]);
        float4v acc[NCO];
#pragma unroll
        for (int t = 0; t < NCO; t++) acc[t] = bias[t];
#pragma unroll
        for (int dy = 0; dy < 3; dy++) {
            short8* row = win[(i + dy) % 3];
#pragma unroll
            for (int dx = 0; dx < 3; dx++) {
                int tap = dy * 3 + dx;
#pragma unroll
                for (int t = 0; t < NCO; t++)
                    acc[t] = __builtin_amdgcn_mfma_f32_16x16x32_bf16(wf[tap * NCO + t], row[dx], acc[t], 0, 0, 0);
            }
        }
        if (OUTF32) {
            float* out = (float*)outv + b * PIMG;
            if (quad == 0) out[y * PW + x0 + n16] = acc[0][0];
        } else {
            bf16* out = (bf16*)outv + (size_t)b * NN * NN * 32;
            bf16* pp = out + ((size_t)y * NN + x0 + n16) * 32 + quad * 4;
#pragma unroll
            for (int t = 0; t < NCO; t++) {
                s4v pk;
#pragma unroll
                for (int r = 0; r < 4; r++) {
                    float v = acc[t][r];
                    if (RELU) v = fmaxf(v, 0.f);
                    bf16 h = __float2bfloat16(v);
                    pk[r] = *reinterpret_cast<short*>(&h);
                }
                *(s4v*)(pp + t * 16) = pk;
            }
        }
    }
}

// ---- final output: 3 f32 copies of padded X ----
__global__ void k_output(const float* __restrict__ X, float* __restrict__ out)
{
    int idx = blockIdx.x * 256 + threadIdx.x;
    if (idx < BNN) {
        int b = idx >> 18;
        int p = idx & (NN * NN - 1);
        int y = p >> 9, x = p & (NN - 1);
        float v = X[b * PIMG + y * PW + x];
        out[idx] = v;
        out[idx + BNN] = v;
        out[idx + 2 * BNN] = v;
    }
}

extern "C" void kernel_launch(void* const* d_in, const int* in_sizes, int n_in,
                              void* d_out, int out_size, void* d_ws, size_t ws_size,
                              hipStream_t stream)
{
    const float* x0    = (const float*)d_in[1];
    const float* sg    = (const float*)d_in[2];
    const float* theta = (const float*)d_in[3];
    const float* w1    = (const float*)d_in[5];
    const float* b1    = (const float*)d_in[6];
    const float* w2    = (const float*)d_in[7];
    const float* b2    = (const float*)d_in[8];
    const float* w3    = (const float*)d_in[9];
    const float* b3    = (const float*)d_in[10];
    const float* w4    = (const float*)d_in[11];
    const float* steps = (const float*)d_in[12];

    float* ws = (float*)d_ws;
    float* XP  = ws + O_XP + POFF;    // origin-adjusted padded pointers
    float* ZP  = ws + O_ZP + POFF;
    float* NOP = ws + O_NOP + POFF;
    float* SP = ws + O_SP;
    float* Q  = ws + O_Q;
    bf16* wr  = (bf16*)(ws + O_WR);
    bf16* h1  = (bf16*)(ws + O_H);
    bf16* h2  = (bf16*)(ws + O_H + H_FLOATS);

    k_params<<<1, 32, 0, stream>>>(theta, ws);
    k_init_pad<<<(2 * PIMG + 255) / 256, 256, 0, stream>>>(x0, ws + O_XP, ws + O_NOP);
    k_prep_w<<<(2 * 27648 + 3 * 4608 + 255) / 256, 256, 0, stream>>>(w2, w3, w4, wr);

    for (int n = 0; n < NL; n++) {
        // path 1: XP -> radon -> filter(sino - .) -> backproj -> ZP
        k_radon<<<dim3(23, NA, NB), 256, 0, stream>>>(XP, ws, SP);
        k_filter<<<dim3(3, NB * NA), 256, 0, stream>>>(SP, sg, Q, 1);
        k_backproj_update<<<dim3(32, 32, NB), 256, 0, stream>>>(Q, XP, nullptr, ws, steps, n, 1.0f, ZP);

        // denoiser (batched grid.z): XP -> h1 -> h2 -> h1 -> NOP
        k_conv1_hwc<<<dim3(NN * NN / 256, NB), 256, 0, stream>>>(XP, w1 + n * 288, b1 + n * 32, h1);
        k_conv_stream<2, true, true, false><<<dim3(32, 16, NB), 256, 0, stream>>>(
            h1, wr + WR2_OFF + n * 9216, b2 + n * 32, h2);
        k_conv_stream<2, true, true, false><<<dim3(32, 16, NB), 256, 0, stream>>>(
            h2, wr + WR3_OFF + n * 9216, b3 + n * 32, h1);
        k_conv_stream<1, false, false, true><<<dim3(32, 16, NB), 256, 0, stream>>>(
            h1, wr + WR4_OFF + n * 4608, nullptr, NOP);

        // path 2: NOP -> radon -> filter -> backproj -> XP = ZP + NOP - step*bp
        k_radon<<<dim3(23, NA, NB), 256, 0, stream>>>(NOP, ws, SP);
        k_filter<<<dim3(3, NB * NA), 256, 0, stream>>>(SP, nullptr, Q, 0);
        k_backproj_update<<<dim3(32, 32, NB), 256, 0, stream>>>(Q, ZP, NOP, ws, steps, n, -1.0f, XP);
    }

    k_output<<<BNN / 256, 256, 0, stream>>>(XP, (float*)d_out);
}

// Round 7
// 490.045 us; speedup vs baseline: 8.2107x; 1.4038x over previous
//
#include <hip/hip_runtime.h>
#include <hip/hip_bf16.h>

typedef __hip_bfloat16 bf16;
typedef __attribute__((ext_vector_type(8))) short short8;
typedef __attribute__((ext_vector_type(4))) short s4v;
typedef __attribute__((ext_vector_type(4))) float float4v;

#define NN 512      // image N
#define NA 30       // angles
#define ND 729      // detectors
#define NB 2        // batch
#define NL 3        // iterations
#define BNN (NB*NN*NN)     // 524288
#define BAD (NB*NA*ND)     // 43740

// padded image layout: PH x PW, logical (0,0) at physical (2,2)
#define PW 520
#define PH 516
#define PIMG (PH*PW)       // 268320
#define POFF (2*PW + 2)    // 1042

// ---- workspace float offsets ----
#define O_CS 0
#define O_SN 32
#define O_XP 64                       // 2*PIMG  (current X, padded)
#define O_YP (O_XP + 2*PIMG)          // 2*PIMG  (Y = X + noise, padded)
#define O_SP (O_YP + 2*PIMG)          // BAD
#define O_Q  (O_SP + BAD)             // BAD
#define O_WR (O_Q + BAD)              // bf16 region: 69120 bf16 = 34560 floats
#define O_H  (((O_WR + 34560) + 15) & ~15)
// h1/h2: each NB*32*NN*NN bf16 = 8388608 floats

#define H_FLOATS (NB * 32 * NN * NN / 2)

// repacked weight bf16 offsets within WR region
#define WR2_OFF 0                   // [n][tap][co32][ci32] : 3*9216
#define WR3_OFF 27648               // 3*9216
#define WR4_OFF 55296               // [n][tap][co16][ci32] : 3*4608 (co>0 zero)

// ---- cos/sin of theta ----
__global__ void k_params(const float* __restrict__ theta, float* __restrict__ ws)
{
    int i = threadIdx.x;
    if (i < NA) {
        float t = theta[i];
        ws[O_CS + i] = cosf(t);
        ws[O_SN + i] = sinf(t);
    }
}

// ---- init: XP = padded(x0) (border zero), YP border zero ----
__global__ void k_init_pad(const float* __restrict__ x0, float* __restrict__ XP,
                           float* __restrict__ YP)
{
    int idx = blockIdx.x * 256 + threadIdx.x;
    if (idx >= 2 * PIMG) return;
    int b = idx / PIMG, p = idx % PIMG;
    int y = p / PW, x = p % PW;
    bool interior = (y >= 2 && y < 2 + NN && x >= 2 && x < 2 + NN);
    float v = interior ? x0[b * NN * NN + (y - 2) * NN + (x - 2)] : 0.f;
    XP[idx] = v;
    if (!interior) YP[idx] = 0.f;
}

// ---- repack conv weights to MFMA [tap][co-tile][co16][ci32] bf16 ----
__global__ void k_prep_w(const float* __restrict__ w2, const float* __restrict__ w3,
                         const float* __restrict__ w4, bf16* __restrict__ wr)
{
    int idx = blockIdx.x * 256 + threadIdx.x;
    if (idx < 2 * 27648) {
        const float* w = (idx < 27648) ? w2 : w3;
        int base = (idx < 27648) ? WR2_OFF : WR3_OFF;
        int r = idx % 27648;
        int n = r / 9216; int r2 = r % 9216;
        int tap = r2 / 1024; int r3 = r2 % 1024;
        int co = r3 / 32, ci = r3 % 32;
        wr[base + r] = __float2bfloat16(w[n * 9216 + (co * 32 + ci) * 9 + tap]);
    } else if (idx < 2 * 27648 + 3 * 4608) {
        int r = idx - 2 * 27648;
        int n = r / 4608; int r2 = r % 4608;
        int tap = r2 / 512; int r3 = r2 % 512;
        int co = r3 / 32, ci = r3 % 32;
        float v = (co == 0) ? w4[n * 288 + ci * 9 + tap] : 0.f;
        wr[WR4_OFF + r] = __float2bfloat16(v);
    }
}

// intersect t-interval with constraint: lo < A + tc*coef < hi
__device__ __forceinline__ void isect(float A, float coef, float lo, float hi,
                                      float& tlo, float& thi)
{
    float a = (lo - A) / coef, b = (hi - A) / coef;
    float l = fminf(a, b), h = fmaxf(a, b);
    tlo = fmaxf(tlo, l);
    thi = fminf(thi, h);
}

// ---- radon forward over padded image; chord-clipped t loop ----
__global__ __launch_bounds__(256) void k_radon(const float* __restrict__ img,
    const float* __restrict__ ws, float* __restrict__ out)
{
    int b = blockIdx.z, a = blockIdx.y;
    int wave = threadIdx.x >> 6;
    int lane = threadIdx.x & 63;
    int s_off = lane & 7, t_sub = lane >> 3;
    int s = blockIdx.x * 32 + wave * 8 + s_off;
    float cs = ws[O_CS + a], sn = ws[O_SN + a];
    float s_c = (float)s - 364.0f;
    float A_r = 255.5f + s_c * sn;    // r(t) = A_r + tc*cs
    float A_c = 255.5f + s_c * cs;    // c(t) = A_c - tc*sn

    float tlo = -1e9f, thi = 1e9f;
    isect(A_r, cs, -1.0f, 512.0f, tlo, thi);
    isect(A_c, -sn, -1.0f, 512.0f, tlo, thi);
    float t0f = fmaxf(tlo + 364.0f, 0.0f);
    float t1f = fminf(thi + 364.0f, 728.0f);
    int tb, te;
    if (s >= ND || t0f > t1f) { tb = 729; te = -1; }
    else { tb = (int)ceilf(t0f); te = (int)floorf(t1f); }

    int wb = tb, we = te;
    wb = min(wb, __shfl_xor(wb, 1, 64)); we = max(we, __shfl_xor(we, 1, 64));
    wb = min(wb, __shfl_xor(wb, 2, 64)); we = max(we, __shfl_xor(we, 2, 64));
    wb = min(wb, __shfl_xor(wb, 4, 64)); we = max(we, __shfl_xor(we, 4, 64));

    const float* im = img + b * PIMG;
    float acc = 0.f;
#pragma unroll 2
    for (int t = wb + t_sub; t <= we; t += 8) {
        if (t >= tb && t <= te) {
            float tc = (float)t - 364.0f;
            float r = fmaf(tc, cs, A_r);
            float c = fmaf(-tc, sn, A_c);
            float rf = floorf(r), cf = floorf(c);
            float dr = r - rf, dc = c - cf;
            int idx = (int)rf * PW + (int)cf;
            float v00 = im[idx], v01 = im[idx + 1];
            float v10 = im[idx + PW], v11 = im[idx + PW + 1];
            float top = fmaf(dc, v01 - v00, v00);
            float bot = fmaf(dc, v11 - v10, v10);
            acc = fmaf(dr, bot - top, acc + top);
        }
    }
    acc += __shfl_down(acc, 32, 64);
    acc += __shfl_down(acc, 16, 64);
    acc += __shfl_down(acc, 8, 64);
    if (t_sub == 0 && s < ND) out[(b * NA + a) * ND + s] = acc;
}

// ---- ramp filter as direct odd-tap convolution: q = sino - scale*conv(sp) ----
__global__ void k_filter(const float* __restrict__ sp, const float* __restrict__ sino,
                         float* __restrict__ q)
{
    __shared__ float row[ND];
    __shared__ float taps[364];
    int ba = blockIdx.y;
    const float* src = sp + ba * ND;
    for (int i = threadIdx.x; i < ND; i += 256) row[i] = src[i];
    const float PI2 = 9.86960440108936f;
    for (int i = threadIdx.x; i < 364; i += 256) {
        float m = (float)(2 * i + 1);
        taps[i] = -2.0f / (PI2 * m * m);
    }
    __syncthreads();
    const float scale = 0.0523598775598299f;  // pi/(2A)
    int d = blockIdx.x * 256 + threadIdx.x;
    if (d < ND) {
        float g0 = 0.5f * row[d], g1 = 0.f;
#pragma unroll 4
        for (int j = 0; j < 364; j += 2) {
            int m0 = 2 * j + 1, m1 = 2 * j + 3;
            float l0 = (d - m0 >= 0) ? row[d - m0] : 0.f;
            float r0 = (d + m0 < ND) ? row[d + m0] : 0.f;
            g0 = fmaf(taps[j], l0 + r0, g0);
            float l1 = (d - m1 >= 0) ? row[d - m1] : 0.f;
            float r1 = (d + m1 < ND) ? row[d + m1] : 0.f;
            g1 = fmaf(taps[j + 1], l1 + r1, g1);
        }
        q[ba * ND + d] = sino[ba * ND + d] - scale * (g0 + g1);
    }
}

// ---- LDS-tiled backprojection + update:  out = src1 + steps[n]*bp(q) ----
// optional outcopy: also write 3 flat copies (final output)
__global__ __launch_bounds__(256) void k_backproj_update(const float* __restrict__ q,
    const float* __restrict__ src1, const float* __restrict__ ws,
    const float* __restrict__ steps, int n, float* __restrict__ out,
    float* __restrict__ outcopy)
{
    __shared__ float qt[NA][28];
    __shared__ int dmin_s[NA];
    int b = blockIdx.z;
    int x0 = blockIdx.x * 16, y0 = blockIdx.y * 16;
    int tid = threadIdx.x;
    int lx = tid & 15, ly = tid >> 4;
    const float* qb = q + b * NA * ND;

    for (int idx = tid; idx < NA * 26; idx += 256) {
        int a = idx / 26, j = idx % 26;
        float cs = ws[O_CS + a], sn = ws[O_SN + a];
        float f00 = fmaf(cs, (float)x0 - 255.5f, fmaf(sn, (float)y0 - 255.5f, 364.0f));
        float fmn = f00 + fminf(cs * 15.f, 0.f) + fminf(sn * 15.f, 0.f);
        int dm = (int)floorf(fmn);
        if (j == 0) dmin_s[a] = dm;
        int d = dm + j;
        qt[a][j] = (d >= 0 && d < ND) ? qb[a * ND + d] : 0.f;
    }
    __syncthreads();

    float xc = (float)(x0 + lx) - 255.5f, yc = (float)(y0 + ly) - 255.5f;
    float acc = 0.f;
#pragma unroll
    for (int a = 0; a < NA; a++) {
        float cs = ws[O_CS + a], sn = ws[O_SN + a];
        float f = fmaf(cs, xc, fmaf(sn, yc, 364.0f));
        float lf = floorf(f);
        float w = f - lf;
        int j = (int)lf - dmin_s[a];
        float v0 = qt[a][j], v1 = qt[a][j + 1];
        acc = fmaf(v0, 1.0f - w, fmaf(v1, w, acc));
    }
    int pidx = b * PIMG + (y0 + ly) * PW + (x0 + lx);
    float v = fmaf(steps[n], acc, src1[pidx]);
    out[pidx] = v;
    if (outcopy) {
        int fidx = b * NN * NN + (y0 + ly) * NN + (x0 + lx);
        outcopy[fidx] = v;
        outcopy[fidx + BNN] = v;
        outcopy[fidx + 2 * BNN] = v;
    }
}

// ---- layer 1: direct 1->32 conv, padded f32 in, bf16 HWC out; grid.y = batch ----
__global__ __launch_bounds__(256) void k_conv1_hwc(const float* __restrict__ inb,
    const float* __restrict__ W, const float* __restrict__ B, bf16* __restrict__ outb)
{
    int bz = blockIdx.y;
    const float* in = inb + bz * PIMG;
    bf16* out = outb + (size_t)bz * NN * NN * 32;
    int idx = blockIdx.x * 256 + threadIdx.x;
    int y = idx >> 9, x = idx & (NN - 1);
    float v[9];
#pragma unroll
    for (int dy = 0; dy < 3; dy++)
#pragma unroll
        for (int dx = 0; dx < 3; dx++)
            v[dy * 3 + dx] = in[(y + dy - 1) * PW + (x + dx - 1)];
#pragma unroll
    for (int g = 0; g < 4; g++) {
        short8 pk;
#pragma unroll
        for (int j = 0; j < 8; j++) {
            int co = g * 8 + j;
            float a = B[co];
            const float* w = W + co * 9;
#pragma unroll
            for (int k = 0; k < 9; k++) a = fmaf(v[k], w[k], a);
            a = fmaxf(a, 0.f);
            bf16 h = __float2bfloat16(a);
            pk[j] = *reinterpret_cast<short*>(&h);
        }
        *(short8*)(out + (size_t)idx * 32 + g * 8) = pk;
    }
}

// ---- streaming MFMA implicit-GEMM 3x3 conv, HWC bf16 in (32 ci) ----
// W = A-operand (m=co), pixels = B-operand (n=px). C: col=px, row=co.
// OUTF32 path: writes padded f32 out = addsrc + conv (Y = X + noise fusion).
#define SH 8
template<int NCO, bool RELU, bool HASB, bool OUTF32>
__global__ __launch_bounds__(256) void k_conv_stream(const bf16* __restrict__ inb,
    const bf16* __restrict__ Wr, const float* __restrict__ Bs,
    const float* __restrict__ addsrc, void* __restrict__ outv)
{
    int lane = threadIdx.x & 63;
    int wave = threadIdx.x >> 6;
    int n16 = lane & 15, quad = lane >> 4;
    int b = blockIdx.z;
    int x0 = blockIdx.x * 16;
    int y0 = (blockIdx.y * 4 + wave) * SH;
    const bf16* in = inb + (size_t)b * NN * NN * 32;

    short8 wf[9 * NCO];
#pragma unroll
    for (int tap = 0; tap < 9; tap++)
#pragma unroll
        for (int t = 0; t < NCO; t++)
            wf[tap * NCO + t] = *(const short8*)(Wr + ((tap * NCO + t) * 16 + n16) * 32 + quad * 8);

    bool vx[3];
#pragma unroll
    for (int dx = 0; dx < 3; dx++) {
        int xx = x0 + n16 + dx - 1;
        vx[dx] = (xx >= 0) && (xx < NN);
    }

    short8 win[3][3];
    auto loadrow = [&](int yy, short8* dst) {
        if (yy >= 0 && yy < NN) {
            const bf16* rowp = in + (size_t)yy * NN * 32;
#pragma unroll
            for (int dx = 0; dx < 3; dx++) {
                short8 v = {};
                if (vx[dx]) v = *(const short8*)(rowp + (x0 + n16 + dx - 1) * 32 + quad * 8);
                dst[dx] = v;
            }
        } else {
            dst[0] = short8{}; dst[1] = short8{}; dst[2] = short8{};
        }
    };
    loadrow(y0 - 1, win[0]);
    loadrow(y0,     win[1]);

    float4v bias[NCO];
#pragma unroll
    for (int t = 0; t < NCO; t++)
        bias[t] = HASB ? *(const float4v*)(Bs + t * 16 + quad * 4) : (float4v){0.f, 0.f, 0.f, 0.f};

#pragma unroll
    for (int i = 0; i < SH; i++) {
        int y = y0 + i;
        loadrow(y + 1, win[(i + 2) % 3]);
        float4v acc[NCO];
#pragma unroll
        for (int t = 0; t < NCO; t++) acc[t] = bias[t];
#pragma unroll
        for (int dy = 0; dy < 3; dy++) {
            short8* row = win[(i + dy) % 3];
#pragma unroll
            for (int dx = 0; dx < 3; dx++) {
                int tap = dy * 3 + dx;
#pragma unroll
                for (int t = 0; t < NCO; t++)
                    acc[t] = __builtin_amdgcn_mfma_f32_16x16x32_bf16(wf[tap * NCO + t], row[dx], acc[t], 0, 0, 0);
            }
        }
        if (OUTF32) {
            float* out = (float*)outv + b * PIMG;
            if (quad == 0) {
                int pi = y * PW + x0 + n16;
                out[pi] = addsrc[b * PIMG + pi] + acc[0][0];
            }
        } else {
            bf16* out = (bf16*)outv + (size_t)b * NN * NN * 32;
            bf16* pp = out + ((size_t)y * NN + x0 + n16) * 32 + quad * 4;
#pragma unroll
            for (int t = 0; t < NCO; t++) {
                s4v pk;
#pragma unroll
                for (int r = 0; r < 4; r++) {
                    float v = acc[t][r];
                    if (RELU) v = fmaxf(v, 0.f);
                    bf16 h = __float2bfloat16(v);
                    pk[r] = *reinterpret_cast<short*>(&h);
                }
                *(s4v*)(pp + t * 16) = pk;
            }
        }
    }
}

extern "C" void kernel_launch(void* const* d_in, const int* in_sizes, int n_in,
                              void* d_out, int out_size, void* d_ws, size_t ws_size,
                              hipStream_t stream)
{
    const float* x0    = (const float*)d_in[1];
    const float* sg    = (const float*)d_in[2];
    const float* theta = (const float*)d_in[3];
    const float* w1    = (const float*)d_in[5];
    const float* b1    = (const float*)d_in[6];
    const float* w2    = (const float*)d_in[7];
    const float* b2    = (const float*)d_in[8];
    const float* w3    = (const float*)d_in[9];
    const float* b3    = (const float*)d_in[10];
    const float* w4    = (const float*)d_in[11];
    const float* steps = (const float*)d_in[12];

    float* ws = (float*)d_ws;
    float* XP = ws + O_XP + POFF;     // origin-adjusted padded pointers
    float* YP = ws + O_YP + POFF;
    float* SP = ws + O_SP;
    float* Q  = ws + O_Q;
    bf16* wr  = (bf16*)(ws + O_WR);
    bf16* h1  = (bf16*)(ws + O_H);
    bf16* h2  = (bf16*)(ws + O_H + H_FLOATS);

    k_params<<<1, 32, 0, stream>>>(theta, ws);
    k_init_pad<<<(2 * PIMG + 255) / 256, 256, 0, stream>>>(x0, ws + O_XP, ws + O_YP);
    k_prep_w<<<(2 * 27648 + 3 * 4608 + 255) / 256, 256, 0, stream>>>(w2, w3, w4, wr);

    for (int n = 0; n < NL; n++) {
        // denoiser: XP -> h1 -> h2 -> h1; conv4 epilogue: YP = XP + conv4(h1)
        k_conv1_hwc<<<dim3(NN * NN / 256, NB), 256, 0, stream>>>(XP, w1 + n * 288, b1 + n * 32, h1);
        k_conv_stream<2, true, true, false><<<dim3(32, 16, NB), 256, 0, stream>>>(
            h1, wr + WR2_OFF + n * 9216, b2 + n * 32, nullptr, h2);
        k_conv_stream<2, true, true, false><<<dim3(32, 16, NB), 256, 0, stream>>>(
            h2, wr + WR3_OFF + n * 9216, b3 + n * 32, nullptr, h1);
        k_conv_stream<1, false, false, true><<<dim3(32, 16, NB), 256, 0, stream>>>(
            h1, wr + WR4_OFF + n * 4608, nullptr, XP, YP);

        // single fused physics path (linearity): XP = YP + steps[n]*bp(sino - F(R(YP)))
        k_radon<<<dim3(23, NA, NB), 256, 0, stream>>>(YP, ws, SP);
        k_filter<<<dim3(3, NB * NA), 256, 0, stream>>>(SP, sg, Q);
        k_backproj_update<<<dim3(32, 32, NB), 256, 0, stream>>>(
            Q, YP, ws, steps, n, XP, (n == NL - 1) ? (float*)d_out : nullptr);
    }
}